// Round 1
// baseline (25.506 us; speedup 1.0000x reference)
//
#include <hip/hip_runtime.h>
#include <hip/hip_bf16.h>

// out = value @ Wv + bv + key   (softmax over [.,.,1,1] is identically 1 -> ctx == v)
// M=2048 (batch), N=1024 (d_model out), K=1024 (d_model in)

#define M_DIM 2048
#define N_DIM 1024
#define K_DIM 1024

typedef __attribute__((ext_vector_type(8))) short short8;
typedef __attribute__((ext_vector_type(4))) float f32x4;

constexpr int BM = 64, BN = 64, BK = 64;
constexpr int THREADS = 256;

__device__ inline unsigned int rne_bf16(float f) {
    unsigned u = __builtin_bit_cast(unsigned, f);
    return (u + 0x7FFFu + ((u >> 16) & 1u)) >> 16;
}
__device__ inline unsigned int pack2(float lo, float hi) {
    return rne_bf16(lo) | (rne_bf16(hi) << 16);
}

__global__ __launch_bounds__(THREADS)
void vproj_residual_kernel(const float* __restrict__ key,
                           const float* __restrict__ value,
                           const float* __restrict__ Wv,
                           const float* __restrict__ bv,
                           float* __restrict__ out) {
    // LDS tiles, bf16, XOR-swizzled in 16B chunks to break bank conflicts.
    // As[row][k]  : row stride 64 bf16 (128B), chunk ^= (row&7)
    // Bs[n][k]    : row stride 64 bf16 (128B), chunk ^= ((n>>1)&7)
    __shared__ __align__(16) short As[BM * BK];
    __shared__ __align__(16) short Bs[BN * BK];

    const int tid = threadIdx.x;
    const int bn = blockIdx.x;           // 0..15
    const int bm = blockIdx.y;           // 0..31
    const int row0 = bm * BM;
    const int col0 = bn * BN;

    const int wid = tid >> 6;            // 0..3
    const int lane = tid & 63;
    const int wr = wid >> 1;             // wave row (0..1)
    const int wc = wid & 1;              // wave col (0..1)

    f32x4 acc[2][2] = {};

    // A staging: thread -> (arow, 16-float k strip)
    const int arow = tid >> 2;           // 0..63
    const int ak0 = (tid & 3) * 16;      // k offset in floats
    const int achunk0 = (tid & 3) * 2;   // first 16B chunk index (of 8 per row)
    const int asw = arow & 7;

    // B staging: thread -> (4 n-cols, k-pair index); two sub-iters cover kp 0..31
    const int bj = (tid & 15) * 4;       // n offset
    const int bkp = tid >> 4;            // 0..15 (pair index base)

    for (int kt = 0; kt < K_DIM / BK; ++kt) {
        // ---- stage A tile: value[row0+arow][kt*64 + ak0 .. +16)
        {
            const float* ap = value + (size_t)(row0 + arow) * K_DIM + kt * BK + ak0;
            f32x4 a0 = *(const f32x4*)(ap + 0);
            f32x4 a1 = *(const f32x4*)(ap + 4);
            f32x4 a2 = *(const f32x4*)(ap + 8);
            f32x4 a3 = *(const f32x4*)(ap + 12);
            union { short8 s; unsigned u[4]; } c0, c1;
            c0.u[0] = pack2(a0[0], a0[1]);
            c0.u[1] = pack2(a0[2], a0[3]);
            c0.u[2] = pack2(a1[0], a1[1]);
            c0.u[3] = pack2(a1[2], a1[3]);
            c1.u[0] = pack2(a2[0], a2[1]);
            c1.u[1] = pack2(a2[2], a2[3]);
            c1.u[2] = pack2(a3[0], a3[1]);
            c1.u[3] = pack2(a3[2], a3[3]);
            *(short8*)(&As[arow * 64 + (((achunk0 + 0) ^ asw) << 3)]) = c0.s;
            *(short8*)(&As[arow * 64 + (((achunk0 + 1) ^ asw) << 3)]) = c1.s;
        }
        // ---- stage B tile transposed: Bs[n][k] = Wv[kt*64+k][col0+n]
        #pragma unroll
        for (int s = 0; s < 2; ++s) {
            int kp = bkp + s * 16;                    // pair index 0..31
            int krow = kt * BK + 2 * kp;
            const float* bp = Wv + (size_t)krow * N_DIM + col0 + bj;
            f32x4 b0 = *(const f32x4*)(bp);
            f32x4 b1 = *(const f32x4*)(bp + N_DIM);
            unsigned* bsu = (unsigned*)Bs;
            #pragma unroll
            for (int m = 0; m < 4; ++m) {
                unsigned u = pack2(b0[m], b1[m]);     // lo = k even, hi = k odd
                int n = bj + m;
                int chunk = (kp >> 2) ^ ((n >> 1) & 7);
                bsu[n * 32 + (chunk << 2) + (kp & 3)] = u;
            }
        }
        __syncthreads();

        // ---- compute: two K=32 slabs
        #pragma unroll
        for (int ks = 0; ks < 2; ++ks) {
            short8 afr[2], bfr[2];
            #pragma unroll
            for (int fm = 0; fm < 2; ++fm) {
                int r = wr * 32 + fm * 16 + (lane & 15);
                int chunk = (ks * 4 + (lane >> 4)) ^ (r & 7);
                afr[fm] = *(const short8*)(&As[r * 64 + (chunk << 3)]);
            }
            #pragma unroll
            for (int fn = 0; fn < 2; ++fn) {
                int n = wc * 32 + fn * 16 + (lane & 15);
                int chunk = (ks * 4 + (lane >> 4)) ^ ((n >> 1) & 7);
                bfr[fn] = *(const short8*)(&Bs[n * 64 + (chunk << 3)]);
            }
            #pragma unroll
            for (int fm = 0; fm < 2; ++fm)
                #pragma unroll
                for (int fn = 0; fn < 2; ++fn)
                    acc[fm][fn] = __builtin_amdgcn_mfma_f32_16x16x32_bf16(
                        afr[fm], bfr[fn], acc[fm][fn], 0, 0, 0);
        }
        __syncthreads();
    }

    // ---- epilogue: out = acc + bv[col] + key[row][col]
    #pragma unroll
    for (int fm = 0; fm < 2; ++fm) {
        #pragma unroll
        for (int fn = 0; fn < 2; ++fn) {
            int col = col0 + wc * 32 + fn * 16 + (lane & 15);
            int rbase = row0 + wr * 32 + fm * 16 + ((lane >> 4) * 4);
            float b = bv[col];
            #pragma unroll
            for (int i = 0; i < 4; ++i) {
                int r = rbase + i;
                out[(size_t)r * N_DIM + col] = acc[fm][fn][i] + b + key[(size_t)r * N_DIM + col];
            }
        }
    }
}

extern "C" void kernel_launch(void* const* d_in, const int* in_sizes, int n_in,
                              void* d_out, int out_size, void* d_ws, size_t ws_size,
                              hipStream_t stream) {
    // setup_inputs order: 0 query, 1 key, 2 value, 3 Wq, 4 bq, 5 Wk, 6 bk, 7 Wv, 8 bv, 9 U
    const float* key   = (const float*)d_in[1];
    const float* value = (const float*)d_in[2];
    const float* Wv    = (const float*)d_in[7];
    const float* bv    = (const float*)d_in[8];
    float* out = (float*)d_out;

    dim3 grid(N_DIM / BN, M_DIM / BM);   // (16, 32) = 512 blocks
    dim3 block(THREADS);
    vproj_residual_kernel<<<grid, block, 0, stream>>>(key, value, Wv, bv, out);
}

// Round 2
// 23.421 us; speedup vs baseline: 1.0890x; 1.0890x over previous
//
#include <hip/hip_runtime.h>
#include <hip/hip_bf16.h>

// out = value @ Wv + bv + key   (softmax over [.,.,1,1] is identically 1 -> ctx == v)
// M=2048 (batch), N=1024 (d_model out), K=1024 (d_model in)
//
// Two kernels:
//  K1 convert: value f32 -> Vb bf16 in tiled+swizzled layout;
//              Wv f32 -> WvTb bf16 transposed [n][k] tiled+swizzled.
//  K2 GEMM:    64x64 tiles, BK=64, global_load_lds(16B) staging of pre-swizzled
//              tiles, double-buffered LDS, mfma_f32_16x16x32_bf16, fused
//              bias + residual epilogue in f32.
//
// Tile layout (both Vb and WvTb): tile (t, kt) is 4096 shorts at
// base = (t*16 + kt)*4096; element (r, kk) at r*64 + ((c ^ (r&7))<<3) + j
// where c = kk>>3, j = kk&7.  (XOR swizzle -> conflict-free ds_read_b128.)

#define M_DIM 2048
#define N_DIM 1024
#define K_DIM 1024

typedef __attribute__((ext_vector_type(8))) short short8;
typedef __attribute__((ext_vector_type(4))) float f32x4;

__device__ inline unsigned rne_bf16(float f) {
    unsigned u = __builtin_bit_cast(unsigned, f);
    return (u + 0x7FFFu + ((u >> 16) & 1u)) >> 16;
}
__device__ inline unsigned pack2(float lo, float hi) {
    return rne_bf16(lo) | (rne_bf16(hi) << 16);
}

// ---------------- K1: convert + transpose ----------------
__global__ __launch_bounds__(256)
void convert_kernel(const float* __restrict__ value, const float* __restrict__ Wv,
                    short* __restrict__ Vb, short* __restrict__ WvTb) {
    __shared__ unsigned tr[64 * 33];
    const int b = blockIdx.x, tid = threadIdx.x;
    if (b < 1024) {
        // value -> Vb : thread handles one 16B chunk (8 consecutive k) of one row
        int g = b * 256 + tid;
        int row = g >> 7, ch = g & 127;     // 128 chunks per 1024-wide row
        int kt = ch >> 3, c = ch & 7;
        int tm = row >> 6, r = row & 63;
        const float* p = value + (size_t)row * K_DIM + ch * 8;
        f32x4 a0 = *(const f32x4*)p;
        f32x4 a1 = *(const f32x4*)(p + 4);
        union { short8 s; unsigned u[4]; } o;
        o.u[0] = pack2(a0[0], a0[1]);
        o.u[1] = pack2(a0[2], a0[3]);
        o.u[2] = pack2(a1[0], a1[1]);
        o.u[3] = pack2(a1[2], a1[3]);
        *(short8*)&Vb[(size_t)(tm * 16 + kt) * 4096 + r * 64 + ((c ^ (r & 7)) << 3)] = o.s;
    } else {
        // Wv -> WvTb : one 64x64 tile per block, transpose via LDS (u32 = bf16 k-pair)
        int b2 = b - 1024;
        int tn = b2 & 15, kt = b2 >> 4;
        #pragma unroll
        for (int s = 0; s < 2; ++s) {
            int kp = (tid >> 4) + s * 16;           // k-pair index 0..31
            int n4 = (tid & 15) * 4;
            const float* bp = Wv + (size_t)(kt * 64 + 2 * kp) * N_DIM + tn * 64 + n4;
            f32x4 b0 = *(const f32x4*)bp;
            f32x4 b1 = *(const f32x4*)(bp + N_DIM);
            #pragma unroll
            for (int m = 0; m < 4; ++m)
                tr[(n4 + m) * 33 + kp] = pack2(b0[m], b1[m]);   // (k even, k odd)
        }
        __syncthreads();
        int n = tid >> 2;
        #pragma unroll
        for (int h = 0; h < 2; ++h) {
            int c = (tid & 3) + 4 * h;              // chunk 0..7
            union { short8 s; unsigned u[4]; } o;
            #pragma unroll
            for (int p = 0; p < 4; ++p)
                o.u[p] = tr[n * 33 + c * 4 + p];    // shorts = kk 8c..8c+7 in order
            *(short8*)&WvTb[(size_t)(tn * 16 + kt) * 4096 + n * 64 + ((c ^ (n & 7)) << 3)] = o.s;
        }
    }
}

// ---------------- K2: bf16 GEMM with fused epilogue ----------------
__device__ inline void gl_lds16(const short* g, short* l) {
    __builtin_amdgcn_global_load_lds((const __attribute__((address_space(1))) void*)g,
                                     (__attribute__((address_space(3))) void*)l,
                                     16, 0, 0);
}

__global__ __launch_bounds__(256)
void gemm_kernel(const short* __restrict__ Vb, const short* __restrict__ WvTb,
                 const float* __restrict__ key, const float* __restrict__ bv,
                 float* __restrict__ out) {
    __shared__ __align__(16) short As[2][4096];
    __shared__ __align__(16) short Bs[2][4096];

    const int tid = threadIdx.x;
    const int bn = blockIdx.x;           // 0..15 (n tiles)
    const int bm = blockIdx.y;           // 0..31 (m tiles)
    const int lane = tid & 63;
    const int wid = tid >> 6;
    const int wr = wid >> 1;             // 0..1
    const int wc = wid & 1;              // 0..1

    const short* Abase = Vb + (size_t)bm * 16 * 4096;
    const short* Bbase = WvTb + (size_t)bn * 16 * 4096;

    f32x4 acc[2][2] = {};

    auto stage = [&](int buf, int kt) {
        const short* ga = Abase + (size_t)kt * 4096 + tid * 8;
        const short* gb = Bbase + (size_t)kt * 4096 + tid * 8;
        gl_lds16(ga,        &As[buf][tid * 8]);
        gl_lds16(ga + 2048, &As[buf][2048 + tid * 8]);
        gl_lds16(gb,        &Bs[buf][tid * 8]);
        gl_lds16(gb + 2048, &Bs[buf][2048 + tid * 8]);
    };

    auto compute = [&](int buf) {
        #pragma unroll
        for (int ks = 0; ks < 2; ++ks) {
            short8 afr[2], bfr[2];
            const int g = ks * 4 + (lane >> 4);      // chunk index of this k-slab
            #pragma unroll
            for (int fm = 0; fm < 2; ++fm) {
                int r = wr * 32 + fm * 16 + (lane & 15);
                afr[fm] = *(const short8*)&As[buf][r * 64 + ((g ^ (r & 7)) << 3)];
            }
            #pragma unroll
            for (int fn = 0; fn < 2; ++fn) {
                int n = wc * 32 + fn * 16 + (lane & 15);
                bfr[fn] = *(const short8*)&Bs[buf][n * 64 + ((g ^ (n & 7)) << 3)];
            }
            #pragma unroll
            for (int fm = 0; fm < 2; ++fm)
                #pragma unroll
                for (int fn = 0; fn < 2; ++fn)
                    acc[fm][fn] = __builtin_amdgcn_mfma_f32_16x16x32_bf16(
                        afr[fm], bfr[fn], acc[fm][fn], 0, 0, 0);
        }
    };

    stage(0, 0);
    __syncthreads();
    #pragma unroll 1
    for (int kt = 0; kt < 16; ++kt) {
        if (kt < 15) stage((kt + 1) & 1, kt + 1);   // issue next-tile loads first
        compute(kt & 1);
        __syncthreads();                             // drains vmcnt, flips buffer
    }

    // epilogue: out = acc + bv[col] + key[row][col]
    const int row0 = bm * 64, col0 = bn * 64;
    #pragma unroll
    for (int fm = 0; fm < 2; ++fm) {
        #pragma unroll
        for (int fn = 0; fn < 2; ++fn) {
            int col = col0 + wc * 32 + fn * 16 + (lane & 15);
            int rbase = row0 + wr * 32 + fm * 16 + ((lane >> 4) * 4);
            float b = bv[col];
            #pragma unroll
            for (int i = 0; i < 4; ++i) {
                int r = rbase + i;
                out[(size_t)r * N_DIM + col] = acc[fm][fn][i] + b + key[(size_t)r * N_DIM + col];
            }
        }
    }
}

extern "C" void kernel_launch(void* const* d_in, const int* in_sizes, int n_in,
                              void* d_out, int out_size, void* d_ws, size_t ws_size,
                              hipStream_t stream) {
    // setup_inputs order: 0 query, 1 key, 2 value, 3 Wq, 4 bq, 5 Wk, 6 bk, 7 Wv, 8 bv, 9 U
    const float* key   = (const float*)d_in[1];
    const float* value = (const float*)d_in[2];
    const float* Wv    = (const float*)d_in[7];
    const float* bv    = (const float*)d_in[8];
    float* out = (float*)d_out;

    short* Vb   = (short*)d_ws;                       // 2048*1024 bf16 = 4 MB
    short* WvTb = (short*)d_ws + (size_t)M_DIM * N_DIM; // 1024*1024 bf16 = 2 MB

    convert_kernel<<<1024 + 256, 256, 0, stream>>>(value, Wv, Vb, WvTb);
    gemm_kernel<<<dim3(N_DIM / 64, M_DIM / 64), 256, 0, stream>>>(Vb, WvTb, key, bv, out);
}